// Round 10
// baseline (780.244 us; speedup 1.0000x reference)
//
#include <hip/hip_runtime.h>

// ConvLSTM2D x2, 4-step temporal blocking, 5 launches. B=4 T=16 H=W=64 C=F=32.
// Launch j: L1 computes t=4j..4j+3 (j=0..3); L2 computes t=4j-4..4j-1 (j=1..4).
// Block owns 2 rows; redundant halo window 8/6/4/2 rows over steps s=0..3.
// h window: one 10-row LDS buffer updated in place (step s reads rows [s,9-s],
// written by step s-1). c: 6-row fp32 LDS, in-place RMW. x restaged per step.
// h1: 8 global planes (t%8); h2,c: parity planes written only at final step.
// Weights streamed from L2 per tap (no register arrays -> no scratch spill).

typedef __bf16 bf16x8 __attribute__((ext_vector_type(8)));
typedef float f32x4 __attribute__((ext_vector_type(4)));

#define WPK_ELEMS 73728   // per layer: 18 kchunks * 8 ntiles * 64 lanes * 8
#define PLANE 524288      // 4*64*64*32 elems per plane

__device__ __forceinline__ float fsigmoid(float z) {
    return 1.0f / (1.0f + __expf(-z));
}
__device__ __forceinline__ float ftanh(float z) {
    z = fminf(15.0f, fmaxf(-15.0f, z));
    float e = __expf(2.0f * z);
    return (e - 1.0f) / (e + 1.0f);
}

__global__ __launch_bounds__(256) void pack_weights(
    const float* __restrict__ wk1, const float* __restrict__ wr1,
    const float* __restrict__ wk2, const float* __restrict__ wr2,
    __bf16* __restrict__ wpk)
{
    int i = blockIdx.x * 256 + threadIdx.x;
    if (i >= 2 * WPK_ELEMS) return;
    int layer = i / WPK_ELEMS;
    int r = i - layer * WPK_ELEMS;
    int j2 = r & 7;
    int L  = (r >> 3) & 63;
    int nt = (r >> 9) & 7;
    int cix = r >> 12;
    int tap = cix >> 1, src = cix & 1;
    int s = ((L >> 4) << 3) + j2;
    int gate = nt & 3;
    int f = ((nt >> 2) << 4) + (L & 15);
    int n = (gate << 5) + f;
    const float* w = layer ? (src ? wr2 : wk2) : (src ? wr1 : wk1);
    wpk[i] = (__bf16)w[(tap * 32 + s) * 128 + n];
}

__device__ __forceinline__ bf16x8 cvt8(const float* p) {
    const float4 f0 = *(const float4*)p;
    const float4 f1 = *(const float4*)(p + 4);
    bf16x8 v;
    v[0] = (__bf16)f0.x; v[1] = (__bf16)f0.y;
    v[2] = (__bf16)f0.z; v[3] = (__bf16)f0.w;
    v[4] = (__bf16)f1.x; v[5] = (__bf16)f1.y;
    v[6] = (__bf16)f1.z; v[7] = (__bf16)f1.w;
    return v;
}

#define MFMA8(A0, A1, WP, ACC)                                                            \
    ACC[0][0] = __builtin_amdgcn_mfma_f32_16x16x32_bf16(A0, WP[0],   ACC[0][0], 0, 0, 0); \
    ACC[0][1] = __builtin_amdgcn_mfma_f32_16x16x32_bf16(A0, WP[64],  ACC[0][1], 0, 0, 0); \
    ACC[0][2] = __builtin_amdgcn_mfma_f32_16x16x32_bf16(A0, WP[128], ACC[0][2], 0, 0, 0); \
    ACC[0][3] = __builtin_amdgcn_mfma_f32_16x16x32_bf16(A0, WP[192], ACC[0][3], 0, 0, 0); \
    ACC[1][0] = __builtin_amdgcn_mfma_f32_16x16x32_bf16(A1, WP[0],   ACC[1][0], 0, 0, 0); \
    ACC[1][1] = __builtin_amdgcn_mfma_f32_16x16x32_bf16(A1, WP[64],  ACC[1][1], 0, 0, 0); \
    ACC[1][2] = __builtin_amdgcn_mfma_f32_16x16x32_bf16(A1, WP[128], ACC[1][2], 0, 0, 0); \
    ACC[1][3] = __builtin_amdgcn_mfma_f32_16x16x32_bf16(A1, WP[192], ACC[1][3], 0, 0, 0);

struct AccT { f32x4 a[2][4]; };

__device__ __forceinline__ void unit_compute(
    AccT& A, const __bf16* xb, const __bf16* hb, const bf16x8* wpkv,
    int rowW, int fh, int mp, int s, bool skipH,
    int c, int q8, int L, const float* bv0, const float* bv1)
{
    #pragma unroll
    for (int m2 = 0; m2 < 2; ++m2) {
        #pragma unroll
        for (int g = 0; g < 4; ++g) {
            const float bg = fh ? bv1[g] : bv0[g];
            A.a[m2][g] = (f32x4){bg, bg, bg, bg};
        }
    }
    #pragma unroll
    for (int tap = 0; tap < 9; ++tap) {
        const int dyk = tap / 3, dxk = tap - dyk * 3;
        const int ccx = mp * 32 + c + dxk;
        const int bx = ((rowW + dyk) * 66 + ccx) * 36 + q8;
        const bf16x8 a0 = *(const bf16x8*)(xb + bx);
        const bf16x8 a1 = *(const bf16x8*)(xb + bx + 576);
        const bf16x8* wpx = wpkv + (size_t)((tap * 2) * 8 + fh * 4) * 64 + L;
        MFMA8(a0, a1, wpx, A.a);
        if (!skipH) {
            const int bh = ((s + rowW + dyk) * 66 + ccx) * 36 + q8;
            const bf16x8 h0 = *(const bf16x8*)(hb + bh);
            const bf16x8 h1v = *(const bf16x8*)(hb + bh + 576);
            const bf16x8* wph = wpkv + (size_t)((tap * 2 + 1) * 8 + fh * 4) * 64 + L;
            MFMA8(h0, h1v, wph, A.a);
        }
    }
}

__device__ __forceinline__ void unit_epilogue(
    AccT& A, __bf16* hb, float* cb,
    int rowW, int fh, int mp, int s, int yy,
    int T0, bool firstT, int layer, int b, int y0,
    const float* cglob, float* cw,
    __bf16* h1buf, __bf16* h2w, float* out,
    int c, int q)
{
    const int f = fh * 16 + c;
    const int rc = yy - (y0 - 2);
    const int rhw = (s + 1 + rowW) * 66;
    const bool own = (yy == y0) || (yy == y0 + 1);
    const size_t gbase = ((size_t)(b * 64 + yy) * 64) * 32;
    #pragma unroll
    for (int m2 = 0; m2 < 2; ++m2) {
        #pragma unroll
        for (int r = 0; r < 4; ++r) {
            const int px = mp * 32 + m2 * 16 + q * 4 + r;
            const float ig = fsigmoid(A.a[m2][0][r]);
            const float fg = fsigmoid(A.a[m2][1][r]);
            const float gg = ftanh(A.a[m2][2][r]);
            const float og = fsigmoid(A.a[m2][3][r]);
            const size_t gidx = gbase + (size_t)px * 32 + f;
            float cold;
            if (s == 0) cold = firstT ? 0.f : cglob[gidx];
            else        cold = cb[(rc * 64 + px) * 32 + f];
            const float cn = (s == 0 && firstT) ? (ig * gg) : (fg * cold + ig * gg);
            if ((unsigned)rc < 6u) cb[(rc * 64 + px) * 32 + f] = cn;
            const float hv = og * ftanh(cn);
            hb[(rhw + px + 1) * 36 + f] = (__bf16)hv;
            if (own) {
                if (layer) {
                    out[((size_t)(b * 16 + T0 + s) * 4096 + (size_t)yy * 64 + px) * 32 + f] = hv;
                    if (s == 3) { h2w[gidx] = (__bf16)hv; cw[gidx] = cn; }
                } else {
                    h1buf[(size_t)((T0 + s) & 7) * PLANE + gidx] = (__bf16)hv;
                    if (s == 3) cw[gidx] = cn;
                }
            }
        }
    }
}

__global__ __launch_bounds__(1024, 4) void clstm_quad(
    const float* __restrict__ x,
    const __bf16* __restrict__ wpk1, const __bf16* __restrict__ wpk2,
    const float* __restrict__ bias1, const float* __restrict__ bias2,
    __bf16* __restrict__ h1buf,       // 8 planes, t%8
    __bf16* __restrict__ h2buf,       // 2 parity planes
    float* __restrict__ c1,           // 2 parity planes
    float* __restrict__ c2,
    float* __restrict__ out, int j)
{
    __shared__ __bf16 xbuf[10 * 66 * 36];   // input-conv src window (restaged/step)
    __shared__ __bf16 hbuf[10 * 66 * 36];   // h window, in-place across steps
    __shared__ float  cbuf[6 * 64 * 32];    // c window, in-place RMW

    const int blk = blockIdx.x;
    const int xcd = blk & 7;
    const int rest = blk >> 3;              // 0..31
    const int layer = rest >> 4;
    if (layer ? (j < 1) : (j > 3)) return;
    const int grp = xcd * 16 + (rest & 15); // XCD-contiguous, same map both layers
    const int T0 = layer ? 4 * (j - 1) : 4 * j;
    const int R = grp << 1;
    const int b = R >> 6, y0 = R & 63;
    const bool firstT = (T0 == 0);

    const int tid = threadIdx.x;
    const int wid = tid >> 6, L = tid & 63;
    const int c = L & 15, q = L >> 4;
    const int q8 = q * 8;

    const bf16x8* wpkv = (const bf16x8*)(layer ? wpk2 : wpk1);
    const float* bias = layer ? bias2 : bias1;
    float bv0[4], bv1[4];
    #pragma unroll
    for (int g = 0; g < 4; ++g) {
        bv0[g] = bias[g * 32 + c];
        bv1[g] = bias[g * 32 + 16 + c];
    }

    const float* cglob = (layer ? c2 : c1) + (size_t)((j - 1) & 1) * PLANE;
    float* cw = (layer ? c2 : c1) + (size_t)(j & 1) * PLANE;
    __bf16* h2w = h2buf + (size_t)(j & 1) * PLANE;

    for (int s = 0; s < 4; ++s) {
        const int t = T0 + s;
        const int winlo = y0 - 3 + s;
        const int rows_x = 10 - 2 * s;

        // ---- stage xbuf: input-conv source rows winlo-1 .. winlo-2+rows_x ----
        {
            const float*  xs = x + (size_t)(b * 16 + t) * 131072;
            const __bf16* hs = h1buf + (size_t)(t & 7) * PLANE;
            for (int i = tid; i < rows_x * 264; i += 1024) {
                const int g = i & 3, rc2 = i >> 2;
                const int cc = rc2 % 66, rw = rc2 / 66;
                const int yy = winlo - 1 + rw, xc = cc - 1;
                bf16x8 v = {};
                if ((unsigned)yy < 64u && (unsigned)xc < 64u) {
                    if (layer) v = *(const bf16x8*)(hs + (((size_t)(b * 64 + yy)) * 64 + xc) * 32 + g * 8);
                    else       v = cvt8(xs + (((size_t)yy * 64 + xc) * 32 + g * 8));
                }
                *(bf16x8*)(xbuf + (rw * 66 + cc) * 36 + g * 8) = v;
            }
        }
        if (s == 0) {
            if (!firstT) {
                const __bf16* rs = layer ? (h2buf + (size_t)((j - 1) & 1) * PLANE)
                                         : (h1buf + (size_t)((T0 - 1) & 7) * PLANE);
                for (int i = tid; i < 2640; i += 1024) {
                    const int g = i & 3, rc2 = i >> 2;
                    const int cc = rc2 % 66, rw = rc2 / 66;
                    const int yy = y0 - 4 + rw, xc = cc - 1;
                    bf16x8 v = {};
                    if ((unsigned)yy < 64u && (unsigned)xc < 64u)
                        v = *(const bf16x8*)(rs + (((size_t)(b * 64 + yy)) * 64 + xc) * 32 + g * 8);
                    *(bf16x8*)(hbuf + (rw * 66 + cc) * 36 + g * 8) = v;
                }
            } else {
                for (int i = tid; i < 2970; i += 1024)
                    *(bf16x8*)(hbuf + i * 8) = (bf16x8){};
            }
        }
        __syncthreads();

        // ---- compute units: (rowW, fh, mp), <=2 per wave, static acc names ----
        const int nu = (8 - 2 * s) * 4;
        const int u0 = wid, u1 = wid + 16;
        AccT A0, A1;
        int rw0 = 0, fh0 = 0, mp0 = 0, yy0 = 0;
        int rw1 = 0, fh1 = 0, mp1 = 0, yy1 = 0;
        bool v0 = false, v1 = false;
        const bool skipH = (s == 0) && firstT;
        if (u0 < nu) {
            rw0 = u0 >> 2; fh0 = (u0 >> 1) & 1; mp0 = u0 & 1;
            yy0 = winlo + rw0;
            v0 = ((unsigned)yy0 < 64u);
            if (v0) unit_compute(A0, xbuf, hbuf, wpkv, rw0, fh0, mp0, s, skipH, c, q8, L, bv0, bv1);
        }
        if (u1 < nu) {
            rw1 = u1 >> 2; fh1 = (u1 >> 1) & 1; mp1 = u1 & 1;
            yy1 = winlo + rw1;
            v1 = ((unsigned)yy1 < 64u);
            if (v1) unit_compute(A1, xbuf, hbuf, wpkv, rw1, fh1, mp1, s, skipH, c, q8, L, bv0, bv1);
        }
        __syncthreads();

        // ---- epilogue (writes hbuf in place + cbuf + global own rows) ----
        if (v0) unit_epilogue(A0, hbuf, cbuf, rw0, fh0, mp0, s, yy0, T0, firstT,
                              layer, b, y0, cglob, cw, h1buf, h2w, out, c, q);
        if (v1) unit_epilogue(A1, hbuf, cbuf, rw1, fh1, mp1, s, yy1, T0, firstT,
                              layer, b, y0, cglob, cw, h1buf, h2w, out, c, q);
    }
}

extern "C" void kernel_launch(void* const* d_in, const int* in_sizes, int n_in,
                              void* d_out, int out_size, void* d_ws, size_t ws_size,
                              hipStream_t stream)
{
    const float* x   = (const float*)d_in[0];
    const float* k1  = (const float*)d_in[1];
    const float* rk1 = (const float*)d_in[2];
    const float* b1  = (const float*)d_in[3];
    const float* k2  = (const float*)d_in[4];
    const float* rk2 = (const float*)d_in[5];
    const float* b2  = (const float*)d_in[6];
    float* out = (float*)d_out;

    __bf16* wpk1  = (__bf16*)d_ws;
    __bf16* wpk2  = wpk1 + WPK_ELEMS;
    __bf16* h1buf = wpk2 + WPK_ELEMS;                     // 8 planes bf16
    __bf16* h2buf = h1buf + 8 * (size_t)PLANE;            // 2 planes bf16
    float*  c1    = (float*)(h2buf + 2 * (size_t)PLANE);  // 2 planes fp32
    float*  c2    = c1 + 2 * (size_t)PLANE;

    pack_weights<<<(2 * WPK_ELEMS + 255) / 256, 256, 0, stream>>>(k1, rk1, k2, rk2, wpk1);

    for (int j = 0; j <= 4; ++j) {
        clstm_quad<<<256, 1024, 0, stream>>>(
            x, wpk1, wpk2, b1, b2, h1buf, h2buf, c1, c2, out, j);
    }
}